// Round 1
// baseline (2756.026 us; speedup 1.0000x reference)
//
#include <hip/hip_runtime.h>
#include <math.h>

#define N_NODES 32768
#define N_EDGES 524288
#define NODE_DIM 128
#define HIDDEN 256
#define EDGE_DIM 32
#define MIN_K (2*NODE_DIM + EDGE_DIM)   // 288
#define TE 32                           // edges per block

__device__ __forceinline__ float silu_f(float v) {
    return v / (1.0f + __expf(-v));
}

// Detect whether edge_index buffer is int64 (jax x64 on) or int32.
// Values are node ids in [0, 32768): if int64, every high 32-bit word is 0.
__global__ void detect_idx_kernel(const unsigned int* __restrict__ ew, int* __restrict__ flag) {
    if (threadIdx.x == 0 && blockIdx.x == 0) {
        int is64 = 1;
        for (int i = 0; i < 64; ++i) {
            if (ew[2 * i + 1] != 0u) { is64 = 0; break; }
        }
        *flag = is64;
    }
}

// out = [h (N*128), x (N*3)]  (d_out is poisoned before every call)
__global__ void init_out_kernel(const float4* __restrict__ h4, const float4* __restrict__ x4,
                                float4* __restrict__ out4) {
    const int NH4 = N_NODES * NODE_DIM / 4;
    const int NX4 = N_NODES * 3 / 4;
    int i = blockIdx.x * blockDim.x + threadIdx.x;
    if (i < NH4) out4[i] = h4[i];
    else if (i < NH4 + NX4) out4[i] = x4[i - NH4];
}

__global__ __launch_bounds__(256, 4)
void egnn_kernel(const float* __restrict__ h, const float* __restrict__ x,
                 const void* __restrict__ ei, const float* __restrict__ dist,
                 const float* __restrict__ We1, const float* __restrict__ be1,
                 const float* __restrict__ We2, const float* __restrict__ be2,
                 const float* __restrict__ Wn1, const float* __restrict__ bn1,
                 const float* __restrict__ Wn2, const float* __restrict__ bn2,
                 const float* __restrict__ Wc1, const float* __restrict__ bc1,
                 const float* __restrict__ Wc2,
                 const int* __restrict__ flag,
                 float* __restrict__ out)
{
    // m_input tile [e][k], k = 0..287; row padded to 292 (1168 B, 16B-aligned rows)
    __shared__ float smA[TE][292];
    // hidden tile [e][j], j = 0..255; row 260 floats (1040 B, 16B-aligned) — reuses smA
    float (*smH)[260] = (float (*)[260])smA;
    __shared__ int sidx[TE], didx[TE];
    __shared__ float cw_s[TE];

    const int t = threadIdx.x;
    const int ebase = blockIdx.x * TE;
    const int is64 = *flag;

    // ---- 1. load edge indices ----
    if (t < 2 * TE) {
        int e = t & (TE - 1);
        int which = t >> 5;  // 0 = src, 1 = dst
        long long pos = (long long)which * N_EDGES + (ebase + e);
        int idx = is64 ? (int)((const long long*)ei)[pos] : ((const int*)ei)[pos];
        if (which == 0) sidx[e] = idx; else didx[e] = idx;
    }
    __syncthreads();

    // ---- 2. gather h[src], h[dst] into smA + edge MLP -> smA[e][256..287] ----
    {
        // 2048 float4 items: per wave, one edge's src+dst rows (fully coalesced 512B runs)
        #pragma unroll
        for (int it = 0; it < 8; ++it) {
            int id = it * 256 + t;
            int q = id & 31;            // float4 index within 128-dim half
            int half = (id >> 5) & 1;   // 0 = src, 1 = dst
            int e = id >> 6;
            int node = half ? didx[e] : sidx[e];
            float4 v = *(const float4*)&h[node * NODE_DIM + 4 * q];
            *(float4*)&smA[e][half * NODE_DIM + 4 * q] = v;
        }
        // edge attr: 8 threads per edge, 4 outputs each
        int e = t >> 3;
        int j2b = (t & 7) * 4;
        float d = dist[ebase + e];
        float t1[EDGE_DIM];
        #pragma unroll
        for (int j = 0; j < EDGE_DIM; ++j) t1[j] = silu_f(d * We1[j] + be1[j]);
        float4 bo = *(const float4*)&be2[j2b];
        float o0 = bo.x, o1 = bo.y, o2 = bo.z, o3 = bo.w;
        #pragma unroll
        for (int j = 0; j < EDGE_DIM; ++j) {
            float4 w = *(const float4*)&We2[j * EDGE_DIM + j2b];
            o0 += t1[j] * w.x; o1 += t1[j] * w.y; o2 += t1[j] * w.z; o3 += t1[j] * w.w;
        }
        *(float4*)&smA[e][2 * NODE_DIM + j2b] = make_float4(o0, o1, o2, o3);
    }
    __syncthreads();

    // ---- 3. GEMM1: [32 x 288] @ [288 x 256], n-path and c-path together ----
    const int tj = t & 63;   // 64 j-groups of 4 hidden units
    const int teg = t >> 6;  // 4 e-groups of 8 edges
    const int j0 = tj * 4;
    const int e0 = teg * 8;
    float accn[8][4], accc[8][4];
    {
        float4 b1 = *(const float4*)&bn1[j0];
        float4 c1 = *(const float4*)&bc1[j0];
        #pragma unroll
        for (int i = 0; i < 8; ++i) {
            accn[i][0] = b1.x; accn[i][1] = b1.y; accn[i][2] = b1.z; accn[i][3] = b1.w;
            accc[i][0] = c1.x; accc[i][1] = c1.y; accc[i][2] = c1.z; accc[i][3] = c1.w;
        }
    }
    for (int k = 0; k < MIN_K; ++k) {
        float4 wn = *(const float4*)&Wn1[k * HIDDEN + j0];
        float4 wc = *(const float4*)&Wc1[k * HIDDEN + j0];
        float a[8];
        #pragma unroll
        for (int i = 0; i < 8; ++i) a[i] = smA[e0 + i][k];  // LDS broadcast
        #pragma unroll
        for (int i = 0; i < 8; ++i) {
            accn[i][0] += a[i] * wn.x; accn[i][1] += a[i] * wn.y;
            accn[i][2] += a[i] * wn.z; accn[i][3] += a[i] * wn.w;
            accc[i][0] += a[i] * wc.x; accc[i][1] += a[i] * wc.y;
            accc[i][2] += a[i] * wc.z; accc[i][3] += a[i] * wc.w;
        }
    }
    __syncthreads();  // smA reads complete before overwrite as smH

    // ---- 4. silu; write n-hidden to LDS; c-path dot Wc2 + wave reduce ----
    {
        #pragma unroll
        for (int i = 0; i < 8; ++i) {
            float4 hv;
            hv.x = silu_f(accn[i][0]); hv.y = silu_f(accn[i][1]);
            hv.z = silu_f(accn[i][2]); hv.w = silu_f(accn[i][3]);
            *(float4*)&smH[e0 + i][j0] = hv;
        }
        float4 w2 = *(const float4*)&Wc2[j0];
        float pc[8];
        #pragma unroll
        for (int i = 0; i < 8; ++i) {
            pc[i] = silu_f(accc[i][0]) * w2.x + silu_f(accc[i][1]) * w2.y
                  + silu_f(accc[i][2]) * w2.z + silu_f(accc[i][3]) * w2.w;
        }
        #pragma unroll
        for (int off = 1; off < 64; off <<= 1) {
            #pragma unroll
            for (int i = 0; i < 8; ++i) pc[i] += __shfl_xor(pc[i], off);
        }
        if (tj < 8) cw_s[e0 + tj] = pc[tj];
    }
    __syncthreads();

    // ---- 5. GEMM2: m = silu(hid) @ Wn2 + bn2; atomic scatter to out_h[dst] ----
    {
        const int td = t & 63;   // d = 2*td, 2*td+1
        const int tg = t >> 6;
        const int ee0 = tg * 8;
        float acc2[8][2];
        float2 b2 = *(const float2*)&bn2[2 * td];
        #pragma unroll
        for (int i = 0; i < 8; ++i) { acc2[i][0] = b2.x; acc2[i][1] = b2.y; }
        for (int j4 = 0; j4 < HIDDEN / 4; ++j4) {
            float2 w0 = *(const float2*)&Wn2[(4 * j4 + 0) * NODE_DIM + 2 * td];
            float2 w1 = *(const float2*)&Wn2[(4 * j4 + 1) * NODE_DIM + 2 * td];
            float2 w2 = *(const float2*)&Wn2[(4 * j4 + 2) * NODE_DIM + 2 * td];
            float2 w3 = *(const float2*)&Wn2[(4 * j4 + 3) * NODE_DIM + 2 * td];
            #pragma unroll
            for (int i = 0; i < 8; ++i) {
                float4 hv = *(const float4*)&smH[ee0 + i][4 * j4];  // LDS broadcast b128
                acc2[i][0] += hv.x * w0.x + hv.y * w1.x + hv.z * w2.x + hv.w * w3.x;
                acc2[i][1] += hv.x * w0.y + hv.y * w1.y + hv.z * w2.y + hv.w * w3.y;
            }
        }
        #pragma unroll
        for (int i = 0; i < 8; ++i) {
            int dn = didx[ee0 + i];
            atomicAdd(&out[dn * NODE_DIM + 2 * td], acc2[i][0]);
            atomicAdd(&out[dn * NODE_DIM + 2 * td + 1], acc2[i][1]);
        }
    }

    // ---- 6. coordinate update (1 thread per edge) ----
    if (t < TE) {
        int s = sidx[t], dn = didx[t];
        float dx = x[s * 3 + 0] - x[dn * 3 + 0];
        float dy = x[s * 3 + 1] - x[dn * 3 + 1];
        float dz = x[s * 3 + 2] - x[dn * 3 + 2];
        float len = fmaxf(sqrtf(dx * dx + dy * dy + dz * dz), 1e-8f);
        float w = cw_s[t] / len;
        float* xo = out + N_NODES * NODE_DIM;
        atomicAdd(&xo[dn * 3 + 0], w * dx);
        atomicAdd(&xo[dn * 3 + 1], w * dy);
        atomicAdd(&xo[dn * 3 + 2], w * dz);
    }
}

extern "C" void kernel_launch(void* const* d_in, const int* in_sizes, int n_in,
                              void* d_out, int out_size, void* d_ws, size_t ws_size,
                              hipStream_t stream) {
    const float* h    = (const float*)d_in[0];
    const float* x    = (const float*)d_in[1];
    const void*  ei   = d_in[2];
    const float* dist = (const float*)d_in[3];
    const float* We1  = (const float*)d_in[4];
    const float* be1  = (const float*)d_in[5];
    const float* We2  = (const float*)d_in[6];
    const float* be2  = (const float*)d_in[7];
    const float* Wn1  = (const float*)d_in[8];
    const float* bn1  = (const float*)d_in[9];
    const float* Wn2  = (const float*)d_in[10];
    const float* bn2  = (const float*)d_in[11];
    const float* Wc1  = (const float*)d_in[12];
    const float* bc1  = (const float*)d_in[13];
    const float* Wc2  = (const float*)d_in[14];
    float* out = (float*)d_out;
    int* flag = (int*)d_ws;

    detect_idx_kernel<<<1, 64, 0, stream>>>((const unsigned int*)ei, flag);

    const int ntot4 = (N_NODES * NODE_DIM + N_NODES * 3) / 4;
    init_out_kernel<<<(ntot4 + 255) / 256, 256, 0, stream>>>(
        (const float4*)h, (const float4*)x, (float4*)out);

    egnn_kernel<<<N_EDGES / TE, 256, 0, stream>>>(
        h, x, ei, dist, We1, be1, We2, be2,
        Wn1, bn1, Wn2, bn2, Wc1, bc1, Wc2, flag, out);
}

// Round 2
// 640.972 us; speedup vs baseline: 4.2998x; 4.2998x over previous
//
#include <hip/hip_runtime.h>
#include <math.h>

#define N_NODES 32768
#define N_EDGES 524288
#define NODE_DIM 128
#define HIDDEN 256
#define EDGE_DIM 32
#define MIN_K 288          // 2*NODE_DIM + EDGE_DIM
#define TE 32              // edges per block
#define ASTR 296           // smA row stride (bf16 elems): 592 B, 16B-aligned
#define HSTR 264           // smH row stride (bf16 elems): 528 B, 16B-aligned

typedef __attribute__((ext_vector_type(8))) short bf16x8;
typedef __attribute__((ext_vector_type(16))) float f32x16;

__device__ __forceinline__ float silu_f(float v) { return v / (1.0f + __expf(-v)); }

__device__ __forceinline__ unsigned short f2bf(float f) {
    union { float f; unsigned int u; } v; v.f = f;
    unsigned int r = (v.u + 0x7fffu + ((v.u >> 16) & 1u)) >> 16;  // RNE
    return (unsigned short)r;
}

// ws layout (bytes): [0..4) idx-width flag; [1024..) W1s swizzled bf16 (512x288);
// then W2s swizzled bf16 (128x256).
#define WS_W1S_OFF 1024
#define WS_W2S_OFF (1024 + 512*288*2)

__global__ void detect_idx_kernel(const unsigned int* __restrict__ ew, int* __restrict__ flag) {
    if (threadIdx.x == 0 && blockIdx.x == 0) {
        int is64 = 1;
        for (int i = 0; i < 64; ++i)
            if (ew[2 * i + 1] != 0u) { is64 = 0; break; }
        *flag = is64;
    }
}

__global__ void init_out_kernel(const float4* __restrict__ h4, const float4* __restrict__ x4,
                                float4* __restrict__ out4) {
    const int NH4 = N_NODES * NODE_DIM / 4;
    const int NX4 = N_NODES * 3 / 4;
    int i = blockIdx.x * blockDim.x + threadIdx.x;
    if (i < NH4) out4[i] = h4[i];
    else if (i < NH4 + NX4) out4[i] = x4[i - NH4];
}

// Swizzle weights into B-fragment order for mfma_f32_32x32x16_bf16:
// frag element idx = ((tile*STEPS + step)*64 + lane)*8 + jj
//   n = tile*32 + (lane&31);  k = step*16 + (lane>>5)*8 + jj
__global__ void prep_kernel(const float* __restrict__ Wn1, const float* __restrict__ Wc1,
                            const float* __restrict__ Wn2,
                            unsigned short* __restrict__ W1s, unsigned short* __restrict__ W2s) {
    int i = blockIdx.x * 256 + threadIdx.x;
    if (i < 512 * 288) {
        int jj = i & 7, lane = (i >> 3) & 63, rest = i >> 9;
        int step = rest % 18, tile = rest / 18;
        int n = tile * 32 + (lane & 31);
        int k = step * 16 + ((lane >> 5) * 8) + jj;
        float v = (n < 256) ? Wn1[k * 256 + n] : Wc1[k * 256 + (n - 256)];
        W1s[i] = f2bf(v);
    } else {
        int i2 = i - 512 * 288;
        if (i2 < 128 * 256) {
            int jj = i2 & 7, lane = (i2 >> 3) & 63, rest = i2 >> 9;
            int step = rest & 15, tile = rest >> 4;
            int d = tile * 32 + (lane & 31);
            int k = step * 16 + ((lane >> 5) * 8) + jj;
            W2s[i2] = f2bf(Wn2[k * 128 + d]);
        }
    }
}

__global__ __launch_bounds__(256, 4)
void egnn_mfma_kernel(const float* __restrict__ h, const float* __restrict__ x,
                      const void* __restrict__ ei, const float* __restrict__ dist,
                      const float* __restrict__ We1, const float* __restrict__ be1,
                      const float* __restrict__ We2, const float* __restrict__ be2,
                      const float* __restrict__ bn1, const float* __restrict__ bn2,
                      const float* __restrict__ bc1, const float* __restrict__ Wc2,
                      const unsigned short* __restrict__ W1s,
                      const unsigned short* __restrict__ W2s,
                      const int* __restrict__ flag,
                      float* __restrict__ out)
{
    __shared__ unsigned short smA[TE * ASTR];   // [e][k0..287] bf16 m_input tile
    __shared__ unsigned short smH[TE * HSTR];   // [e][j0..255] bf16 silu(hidden)
    __shared__ int sidx[TE], didx[TE];
    __shared__ float cw_s[TE];

    const int t = threadIdx.x;
    const int lane = t & 63;
    const int wv = t >> 6;
    const int lo = lane & 31;     // n/col sub-index
    const int hi = lane >> 5;     // half
    const int ebase = blockIdx.x * TE;
    const int is64 = *flag;

    // ---- 1. edge indices + zero cw ----
    if (t < 2 * TE) {
        int e = t & (TE - 1);
        int which = t >> 5;
        long long pos = (long long)which * N_EDGES + (ebase + e);
        int idx = is64 ? (int)((const long long*)ei)[pos] : ((const int*)ei)[pos];
        if (which == 0) sidx[e] = idx; else didx[e] = idx;
        if (t < TE) cw_s[t] = 0.0f;
    }
    __syncthreads();

    // ---- 2. gather h[src],h[dst] -> bf16 smA; edge MLP -> smA[:,256:288] ----
    #pragma unroll
    for (int it = 0; it < 8; ++it) {
        int id = it * 256 + t;
        int q = id & 31;
        int half = (id >> 5) & 1;
        int e = id >> 6;
        int node = half ? didx[e] : sidx[e];
        float4 v = *(const float4*)&h[node * NODE_DIM + 4 * q];
        unsigned int p0 = (unsigned int)f2bf(v.x) | ((unsigned int)f2bf(v.y) << 16);
        unsigned int p1 = (unsigned int)f2bf(v.z) | ((unsigned int)f2bf(v.w) << 16);
        *(uint2*)&smA[e * ASTR + half * NODE_DIM + 4 * q] = make_uint2(p0, p1);
    }
    {
        int e = t >> 3;
        int j2b = (t & 7) * 4;
        float d = dist[ebase + e];
        float4 bo = *(const float4*)&be2[j2b];
        float o0 = bo.x, o1 = bo.y, o2 = bo.z, o3 = bo.w;
        #pragma unroll
        for (int j = 0; j < EDGE_DIM; ++j) {
            float t1 = silu_f(d * We1[j] + be1[j]);
            float4 w = *(const float4*)&We2[j * EDGE_DIM + j2b];
            o0 += t1 * w.x; o1 += t1 * w.y; o2 += t1 * w.z; o3 += t1 * w.w;
        }
        unsigned int p0 = (unsigned int)f2bf(o0) | ((unsigned int)f2bf(o1) << 16);
        unsigned int p1 = (unsigned int)f2bf(o2) | ((unsigned int)f2bf(o3) << 16);
        *(uint2*)&smA[e * ASTR + 2 * NODE_DIM + j2b] = make_uint2(p0, p1);
    }
    __syncthreads();

    // ---- 3. GEMM1: [32 x 288] @ [288 x 512] (Wn1 | Wc1), 4 n-tiles per wave ----
    f32x16 acc0, acc1, acc2, acc3;
    {
        int nb = wv * 128 + lo;  // combined n index of tile 0
        float b0 = (nb < 256) ? bn1[nb] : bc1[nb - 256];
        float b1 = (nb + 32 < 256) ? bn1[nb + 32] : bc1[nb + 32 - 256];
        float b2 = (nb + 64 < 256) ? bn1[nb + 64] : bc1[nb + 64 - 256];
        float b3 = (nb + 96 < 256) ? bn1[nb + 96] : bc1[nb + 96 - 256];
        #pragma unroll
        for (int r = 0; r < 16; ++r) { acc0[r] = b0; acc1[r] = b1; acc2[r] = b2; acc3[r] = b3; }
    }
    {
        const int aoff = lo * ASTR + hi * 8;
        #pragma unroll 3
        for (int step = 0; step < 18; ++step) {
            bf16x8 af = *(const bf16x8*)&smA[aoff + step * 16];
            int base = ((wv * 4 * 18 + step) * 64 + lane) * 8;
            bf16x8 b0 = *(const bf16x8*)&W1s[base];
            bf16x8 b1 = *(const bf16x8*)&W1s[base + 18 * 64 * 8];
            bf16x8 b2 = *(const bf16x8*)&W1s[base + 2 * 18 * 64 * 8];
            bf16x8 b3 = *(const bf16x8*)&W1s[base + 3 * 18 * 64 * 8];
            acc0 = __builtin_amdgcn_mfma_f32_32x32x16_bf16(af, b0, acc0, 0, 0, 0);
            acc1 = __builtin_amdgcn_mfma_f32_32x32x16_bf16(af, b1, acc1, 0, 0, 0);
            acc2 = __builtin_amdgcn_mfma_f32_32x32x16_bf16(af, b2, acc2, 0, 0, 0);
            acc3 = __builtin_amdgcn_mfma_f32_32x32x16_bf16(af, b3, acc3, 0, 0, 0);
        }
    }

    // ---- 4. epilogue: n-waves -> silu -> smH bf16; c-waves -> dot Wc2 + reduce ----
    const int rowbase = 4 * hi;
    if (wv < 2) {
        int jb = wv * 128 + lo;
        #pragma unroll
        for (int r = 0; r < 16; ++r) {
            int e = (r & 3) + 8 * (r >> 2) + rowbase;
            smH[e * HSTR + jb]      = f2bf(silu_f(acc0[r]));
            smH[e * HSTR + jb + 32] = f2bf(silu_f(acc1[r]));
            smH[e * HSTR + jb + 64] = f2bf(silu_f(acc2[r]));
            smH[e * HSTR + jb + 96] = f2bf(silu_f(acc3[r]));
        }
    } else {
        int nc = (wv - 2) * 128 + lo;
        float w0 = Wc2[nc], w1 = Wc2[nc + 32], w2 = Wc2[nc + 64], w3 = Wc2[nc + 96];
        float p[16];
        #pragma unroll
        for (int r = 0; r < 16; ++r)
            p[r] = silu_f(acc0[r]) * w0 + silu_f(acc1[r]) * w1
                 + silu_f(acc2[r]) * w2 + silu_f(acc3[r]) * w3;
        #pragma unroll
        for (int off = 1; off < 32; off <<= 1) {
            #pragma unroll
            for (int r = 0; r < 16; ++r) p[r] += __shfl_xor(p[r], off);
        }
        if (lo == 0) {
            #pragma unroll
            for (int r = 0; r < 16; ++r) {
                int e = (r & 3) + 8 * (r >> 2) + rowbase;
                atomicAdd(&cw_s[e], p[r]);
            }
        }
    }
    __syncthreads();

    // ---- 5. GEMM2: [32 x 256] @ [256 x 128], 1 d-tile per wave; atomic scatter ----
    {
        int d = wv * 32 + lo;
        f32x16 acc;
        float b = bn2[d];
        #pragma unroll
        for (int r = 0; r < 16; ++r) acc[r] = b;
        const int aoff = lo * HSTR + hi * 8;
        #pragma unroll 4
        for (int step = 0; step < 16; ++step) {
            bf16x8 af = *(const bf16x8*)&smH[aoff + step * 16];
            bf16x8 bf = *(const bf16x8*)&W2s[((wv * 16 + step) * 64 + lane) * 8];
            acc = __builtin_amdgcn_mfma_f32_32x32x16_bf16(af, bf, acc, 0, 0, 0);
        }
        #pragma unroll
        for (int r = 0; r < 16; ++r) {
            int e = (r & 3) + 8 * (r >> 2) + rowbase;
            atomicAdd(&out[didx[e] * NODE_DIM + d], acc[r]);
        }
    }

    // ---- 6. coordinate update ----
    if (t < TE) {
        int s = sidx[t], dn = didx[t];
        float dx = x[s * 3 + 0] - x[dn * 3 + 0];
        float dy = x[s * 3 + 1] - x[dn * 3 + 1];
        float dz = x[s * 3 + 2] - x[dn * 3 + 2];
        float len = fmaxf(sqrtf(dx * dx + dy * dy + dz * dz), 1e-8f);
        float w = cw_s[t] / len;
        float* xo = out + N_NODES * NODE_DIM;
        atomicAdd(&xo[dn * 3 + 0], w * dx);
        atomicAdd(&xo[dn * 3 + 1], w * dy);
        atomicAdd(&xo[dn * 3 + 2], w * dz);
    }
}

extern "C" void kernel_launch(void* const* d_in, const int* in_sizes, int n_in,
                              void* d_out, int out_size, void* d_ws, size_t ws_size,
                              hipStream_t stream) {
    const float* h    = (const float*)d_in[0];
    const float* x    = (const float*)d_in[1];
    const void*  ei   = d_in[2];
    const float* dist = (const float*)d_in[3];
    const float* We1  = (const float*)d_in[4];
    const float* be1  = (const float*)d_in[5];
    const float* We2  = (const float*)d_in[6];
    const float* be2  = (const float*)d_in[7];
    const float* Wn1  = (const float*)d_in[8];
    const float* bn1  = (const float*)d_in[9];
    const float* Wn2  = (const float*)d_in[10];
    const float* bn2  = (const float*)d_in[11];
    const float* Wc1  = (const float*)d_in[12];
    const float* bc1  = (const float*)d_in[13];
    const float* Wc2  = (const float*)d_in[14];
    float* out = (float*)d_out;

    int* flag = (int*)d_ws;
    unsigned short* W1s = (unsigned short*)((char*)d_ws + WS_W1S_OFF);
    unsigned short* W2s = (unsigned short*)((char*)d_ws + WS_W2S_OFF);

    detect_idx_kernel<<<1, 64, 0, stream>>>((const unsigned int*)ei, flag);

    const int ntot4 = (N_NODES * NODE_DIM + N_NODES * 3) / 4;
    init_out_kernel<<<(ntot4 + 255) / 256, 256, 0, stream>>>(
        (const float4*)h, (const float4*)x, (float4*)out);

    prep_kernel<<<(512 * 288 + 128 * 256 + 255) / 256, 256, 0, stream>>>(
        Wn1, Wc1, Wn2, W1s, W2s);

    egnn_mfma_kernel<<<N_EDGES / TE, 256, 0, stream>>>(
        h, x, ei, dist, We1, be1, We2, be2,
        bn1, bn2, bc1, Wc2, W1s, W2s, flag, out);
}

// Round 3
// 611.081 us; speedup vs baseline: 4.5101x; 1.0489x over previous
//
#include <hip/hip_runtime.h>
#include <math.h>

#define N_NODES 32768
#define N_EDGES 524288
#define NODE_DIM 128
#define HIDDEN 256
#define EDGE_DIM 32
#define TE 64              // edges per block
#define ASTR 296           // smA row stride (bf16): 592 B, 16B-aligned
#define HSTR 264           // smH row stride (bf16): 528 B, 16B-aligned

typedef __attribute__((ext_vector_type(8))) short bf16x8;
typedef __attribute__((ext_vector_type(16))) float f32x16;

// fast silu: x * rcp(1 + exp(-x)); v_exp + v_rcp quarter-rate, ~5 VALU ops
__device__ __forceinline__ float silu_f(float v) {
    float e = __expf(-v);
    return v * __builtin_amdgcn_rcpf(1.0f + e);
}

// RNE pack (prep kernels only — accuracy where it's cheap)
__device__ __forceinline__ unsigned short f2bf_rne(float f) {
    union { float f; unsigned int u; } v; v.f = f;
    return (unsigned short)((v.u + 0x7fffu + ((v.u >> 16) & 1u)) >> 16);
}

// half-up pack of two floats -> (bf16(a) | bf16(b)<<16) : 2 adds + v_perm
__device__ __forceinline__ unsigned int pkbf(float a, float b) {
    union { float f; unsigned int u; } ua, ub; ua.f = a; ub.f = b;
    return __builtin_amdgcn_perm(ub.u + 0x8000u, ua.u + 0x8000u, 0x07060302u);
}
__device__ __forceinline__ unsigned short f2bf_hu(float f) {
    union { float f; unsigned int u; } v; v.f = f;
    return (unsigned short)((v.u + 0x8000u) >> 16);
}

// ws layout (bytes):
//   0       : idx-width flag
//   1024    : biasC f32[512]   (bn1|bc1 with be2@W1ea folded in)
//   4096    : W1ea f32[32][512] (We2 @ W1[256:288,:])
//   69632   : W1s bf16 swizzled (512 tiles-n x 288 k)
//   364544  : W2s bf16 swizzled (128 x 256)
#define WS_BIAS_OFF 1024
#define WS_W1EA_OFF 4096
#define WS_W1S_OFF  69632
#define WS_W2S_OFF  364544

__global__ void detect_idx_kernel(const unsigned int* __restrict__ ew, int* __restrict__ flag) {
    if (threadIdx.x == 0 && blockIdx.x == 0) {
        int is64 = 1;
        for (int i = 0; i < 64; ++i)
            if (ew[2 * i + 1] != 0u) { is64 = 0; break; }
        *flag = is64;
    }
}

__global__ void init_out_kernel(const float4* __restrict__ h4, const float4* __restrict__ x4,
                                float4* __restrict__ out4) {
    const int NH4 = N_NODES * NODE_DIM / 4;
    const int NX4 = N_NODES * 3 / 4;
    int i = blockIdx.x * blockDim.x + threadIdx.x;
    if (i < NH4) out4[i] = h4[i];
    else if (i < NH4 + NX4) out4[i] = x4[i - NH4];
}

// prep1: W1ea[j][n] = sum_k We2[j][k] * W1[256+k][n];  biasC[n] = b1[n] + sum_k be2[k]*W1[256+k][n]
__global__ void prep1_kernel(const float* __restrict__ Wn1, const float* __restrict__ Wc1,
                             const float* __restrict__ bn1, const float* __restrict__ bc1,
                             const float* __restrict__ We2, const float* __restrict__ be2,
                             float* __restrict__ W1ea, float* __restrict__ biasC) {
    int i = blockIdx.x * 256 + threadIdx.x;
    if (i < 32 * 512) {
        int n = i & 511, j = i >> 9;
        float s = 0.0f;
        #pragma unroll 8
        for (int k = 0; k < 32; ++k)
            s += We2[j * 32 + k] * ((n < 256) ? Wn1[(256 + k) * 256 + n]
                                              : Wc1[(256 + k) * 256 + (n - 256)]);
        W1ea[i] = s;
    } else if (i < 32 * 512 + 512) {
        int n = i - 32 * 512;
        float s = (n < 256) ? bn1[n] : bc1[n - 256];
        #pragma unroll 8
        for (int k = 0; k < 32; ++k)
            s += be2[k] * ((n < 256) ? Wn1[(256 + k) * 256 + n]
                                     : Wc1[(256 + k) * 256 + (n - 256)]);
        biasC[n] = s;
    }
}

// prep2: swizzle into B-fragment order for mfma_f32_32x32x16_bf16
// frag idx = ((tile*STEPS + step)*64 + lane)*8 + jj ; n = tile*32+(lane&31); k = step*16+(lane>>5)*8+jj
__global__ void prep2_kernel(const float* __restrict__ Wn1, const float* __restrict__ Wc1,
                             const float* __restrict__ Wn2, const float* __restrict__ W1ea,
                             unsigned short* __restrict__ W1s, unsigned short* __restrict__ W2s) {
    int i = blockIdx.x * 256 + threadIdx.x;
    if (i < 512 * 288) {
        int jj = i & 7, lane = (i >> 3) & 63, rest = i >> 9;
        int step = rest % 18, tile = rest / 18;
        int n = tile * 32 + (lane & 31);
        int k = step * 16 + ((lane >> 5) * 8) + jj;
        float v;
        if (k < 256) v = (n < 256) ? Wn1[k * 256 + n] : Wc1[k * 256 + (n - 256)];
        else         v = W1ea[(k - 256) * 512 + n];
        W1s[i] = f2bf_rne(v);
    } else {
        int i2 = i - 512 * 288;
        if (i2 < 128 * 256) {
            int jj = i2 & 7, lane = (i2 >> 3) & 63, rest = i2 >> 9;
            int step = rest & 15, tile = rest >> 4;
            int d = tile * 32 + (lane & 31);
            int k = step * 16 + ((lane >> 5) * 8) + jj;
            W2s[i2] = f2bf_rne(Wn2[k * 128 + d]);
        }
    }
}

__global__ __launch_bounds__(256, 2)
void egnn_mfma_kernel(const float* __restrict__ h, const float* __restrict__ x,
                      const void* __restrict__ ei, const float* __restrict__ dist,
                      const float* __restrict__ We1, const float* __restrict__ be1,
                      const float* __restrict__ bn2, const float* __restrict__ Wc2,
                      const float* __restrict__ biasC,
                      const unsigned short* __restrict__ W1s,
                      const unsigned short* __restrict__ W2s,
                      const int* __restrict__ flag,
                      float* __restrict__ out)
{
    __shared__ unsigned short smA[TE * ASTR];   // [e][k0..287] bf16 (h_src|h_dst|t1)
    __shared__ unsigned short smH[TE * HSTR];   // [e][j0..255] bf16 silu(hidden)
    __shared__ int sidx[TE], didx[TE];
    __shared__ float cw_s[TE];

    const int t = threadIdx.x;
    const int lane = t & 63;
    const int wv = t >> 6;
    const int lo = lane & 31;
    const int hi = lane >> 5;
    const int ebase = blockIdx.x * TE;
    const int is64 = *flag;

    // ---- 1. edge indices + zero cw ----
    if (t < 2 * TE) {
        int e = t & (TE - 1);
        int which = t >> 6;              // 0 = src, 1 = dst
        long long pos = (long long)which * N_EDGES + (ebase + e);
        int idx = is64 ? (int)((const long long*)ei)[pos] : ((const int*)ei)[pos];
        if (which == 0) sidx[e] = idx; else didx[e] = idx;
        if (t < TE) cw_s[t] = 0.0f;
    }
    __syncthreads();

    // ---- 2a. gather h[src], h[dst] -> bf16 smA (32B per thread-iter, b128 LDS writes) ----
    #pragma unroll
    for (int it = 0; it < 8; ++it) {
        int id = it * 256 + t;
        int g8 = id & 15;                // 8-float group within a 128-dim half
        int half = (id >> 4) & 1;
        int e = id >> 5;
        int node = half ? didx[e] : sidx[e];
        const float4* p = (const float4*)&h[node * NODE_DIM + 8 * g8];
        float4 v0 = p[0], v1 = p[1];
        unsigned int a0 = pkbf(v0.x, v0.y), a1 = pkbf(v0.z, v0.w);
        unsigned int a2 = pkbf(v1.x, v1.y), a3 = pkbf(v1.z, v1.w);
        *(uint4*)&smA[e * ASTR + half * NODE_DIM + 8 * g8] = make_uint4(a0, a1, a2, a3);
    }
    // ---- 2b. t1 = silu(d*We1+be1) -> smA[:,256:288] (layer2 folded into W1s) ----
    {
        int e = t & 63;
        int w8 = (t >> 6) * 8;
        float d = dist[ebase + e];
        unsigned int q0, q1, q2, q3;
        {
            float s0 = silu_f(d * We1[w8 + 0] + be1[w8 + 0]);
            float s1 = silu_f(d * We1[w8 + 1] + be1[w8 + 1]);
            float s2 = silu_f(d * We1[w8 + 2] + be1[w8 + 2]);
            float s3 = silu_f(d * We1[w8 + 3] + be1[w8 + 3]);
            float s4 = silu_f(d * We1[w8 + 4] + be1[w8 + 4]);
            float s5 = silu_f(d * We1[w8 + 5] + be1[w8 + 5]);
            float s6 = silu_f(d * We1[w8 + 6] + be1[w8 + 6]);
            float s7 = silu_f(d * We1[w8 + 7] + be1[w8 + 7]);
            q0 = pkbf(s0, s1); q1 = pkbf(s2, s3); q2 = pkbf(s4, s5); q3 = pkbf(s6, s7);
        }
        *(uint4*)&smA[e * ASTR + 2 * NODE_DIM + w8] = make_uint4(q0, q1, q2, q3);
    }
    __syncthreads();

    // ---- 3. GEMM1: [64 x 288] @ [288 x 512], 2 e-tiles x 4 n-tiles per wave ----
    f32x16 acc[2][4];
    {
        int nb = wv * 128 + lo;
        float b0 = biasC[nb], b1 = biasC[nb + 32], b2 = biasC[nb + 64], b3 = biasC[nb + 96];
        #pragma unroll
        for (int r = 0; r < 16; ++r) {
            acc[0][0][r] = b0; acc[0][1][r] = b1; acc[0][2][r] = b2; acc[0][3][r] = b3;
            acc[1][0][r] = b0; acc[1][1][r] = b1; acc[1][2][r] = b2; acc[1][3][r] = b3;
        }
    }
    {
        const int aoff0 = lo * ASTR + hi * 8;
        const int aoff1 = (32 + lo) * ASTR + hi * 8;
        #pragma unroll 2
        for (int step = 0; step < 18; ++step) {
            bf16x8 a0 = *(const bf16x8*)&smA[aoff0 + step * 16];
            bf16x8 a1 = *(const bf16x8*)&smA[aoff1 + step * 16];
            int base = ((wv * 4 * 18 + step) * 64 + lane) * 8;
            bf16x8 b0 = *(const bf16x8*)&W1s[base];
            bf16x8 b1 = *(const bf16x8*)&W1s[base + 18 * 64 * 8];
            bf16x8 b2 = *(const bf16x8*)&W1s[base + 2 * 18 * 64 * 8];
            bf16x8 b3 = *(const bf16x8*)&W1s[base + 3 * 18 * 64 * 8];
            acc[0][0] = __builtin_amdgcn_mfma_f32_32x32x16_bf16(a0, b0, acc[0][0], 0, 0, 0);
            acc[1][0] = __builtin_amdgcn_mfma_f32_32x32x16_bf16(a1, b0, acc[1][0], 0, 0, 0);
            acc[0][1] = __builtin_amdgcn_mfma_f32_32x32x16_bf16(a0, b1, acc[0][1], 0, 0, 0);
            acc[1][1] = __builtin_amdgcn_mfma_f32_32x32x16_bf16(a1, b1, acc[1][1], 0, 0, 0);
            acc[0][2] = __builtin_amdgcn_mfma_f32_32x32x16_bf16(a0, b2, acc[0][2], 0, 0, 0);
            acc[1][2] = __builtin_amdgcn_mfma_f32_32x32x16_bf16(a1, b2, acc[1][2], 0, 0, 0);
            acc[0][3] = __builtin_amdgcn_mfma_f32_32x32x16_bf16(a0, b3, acc[0][3], 0, 0, 0);
            acc[1][3] = __builtin_amdgcn_mfma_f32_32x32x16_bf16(a1, b3, acc[1][3], 0, 0, 0);
        }
    }

    // ---- 4. epilogue: waves 0-1 n-path -> silu -> smH; waves 2-3 c-path -> dot Wc2 ----
    const int rowbase = 4 * hi;
    if (wv < 2) {
        int jb = wv * 128 + lo;
        #pragma unroll
        for (int et = 0; et < 2; ++et) {
            #pragma unroll
            for (int r = 0; r < 16; ++r) {
                int e = et * 32 + (r & 3) + 8 * (r >> 2) + rowbase;
                unsigned short* row = &smH[e * HSTR + jb];
                row[0]  = f2bf_hu(silu_f(acc[et][0][r]));
                row[32] = f2bf_hu(silu_f(acc[et][1][r]));
                row[64] = f2bf_hu(silu_f(acc[et][2][r]));
                row[96] = f2bf_hu(silu_f(acc[et][3][r]));
            }
        }
    } else {
        int nc = (wv - 2) * 128 + lo;
        float w0 = Wc2[nc], w1 = Wc2[nc + 32], w2 = Wc2[nc + 64], w3 = Wc2[nc + 96];
        float p[2][16];
        #pragma unroll
        for (int et = 0; et < 2; ++et)
            #pragma unroll
            for (int r = 0; r < 16; ++r)
                p[et][r] = silu_f(acc[et][0][r]) * w0 + silu_f(acc[et][1][r]) * w1
                         + silu_f(acc[et][2][r]) * w2 + silu_f(acc[et][3][r]) * w3;
        #pragma unroll
        for (int off = 1; off < 32; off <<= 1) {
            #pragma unroll
            for (int et = 0; et < 2; ++et)
                #pragma unroll
                for (int r = 0; r < 16; ++r)
                    p[et][r] += __shfl_xor(p[et][r], off);
        }
        if (lo == 0) {
            #pragma unroll
            for (int et = 0; et < 2; ++et)
                #pragma unroll
                for (int r = 0; r < 16; ++r) {
                    int e = et * 32 + (r & 3) + 8 * (r >> 2) + rowbase;
                    atomicAdd(&cw_s[e], p[et][r]);
                }
        }
    }
    __syncthreads();

    // ---- 5. GEMM2: [64 x 256] @ [256 x 128], 1 d-tile x 2 e-tiles per wave ----
    {
        int d = wv * 32 + lo;
        f32x16 c0, c1;
        float b = bn2[d];
        #pragma unroll
        for (int r = 0; r < 16; ++r) { c0[r] = b; c1[r] = b; }
        const int hoff0 = lo * HSTR + hi * 8;
        const int hoff1 = (32 + lo) * HSTR + hi * 8;
        #pragma unroll 4
        for (int step = 0; step < 16; ++step) {
            bf16x8 bf = *(const bf16x8*)&W2s[((wv * 16 + step) * 64 + lane) * 8];
            bf16x8 a0 = *(const bf16x8*)&smH[hoff0 + step * 16];
            bf16x8 a1 = *(const bf16x8*)&smH[hoff1 + step * 16];
            c0 = __builtin_amdgcn_mfma_f32_32x32x16_bf16(a0, bf, c0, 0, 0, 0);
            c1 = __builtin_amdgcn_mfma_f32_32x32x16_bf16(a1, bf, c1, 0, 0, 0);
        }
        #pragma unroll
        for (int r = 0; r < 16; ++r) {
            int e0 = (r & 3) + 8 * (r >> 2) + rowbase;
            atomicAdd(&out[didx[e0] * NODE_DIM + d], c0[r]);
            atomicAdd(&out[didx[e0 + 32] * NODE_DIM + d], c1[r]);
        }
    }

    // ---- 6. coordinate update (wave 0) ----
    if (t < TE) {
        int s = sidx[t], dn = didx[t];
        float dx = x[s * 3 + 0] - x[dn * 3 + 0];
        float dy = x[s * 3 + 1] - x[dn * 3 + 1];
        float dz = x[s * 3 + 2] - x[dn * 3 + 2];
        float len = fmaxf(sqrtf(dx * dx + dy * dy + dz * dz), 1e-8f);
        float w = cw_s[t] / len;
        float* xo = out + N_NODES * NODE_DIM;
        atomicAdd(&xo[dn * 3 + 0], w * dx);
        atomicAdd(&xo[dn * 3 + 1], w * dy);
        atomicAdd(&xo[dn * 3 + 2], w * dz);
    }
}

extern "C" void kernel_launch(void* const* d_in, const int* in_sizes, int n_in,
                              void* d_out, int out_size, void* d_ws, size_t ws_size,
                              hipStream_t stream) {
    const float* h    = (const float*)d_in[0];
    const float* x    = (const float*)d_in[1];
    const void*  ei   = d_in[2];
    const float* dist = (const float*)d_in[3];
    const float* We1  = (const float*)d_in[4];
    const float* be1  = (const float*)d_in[5];
    const float* We2  = (const float*)d_in[6];
    const float* be2  = (const float*)d_in[7];
    const float* Wn1  = (const float*)d_in[8];
    const float* bn1  = (const float*)d_in[9];
    const float* Wn2  = (const float*)d_in[10];
    const float* bn2  = (const float*)d_in[11];
    const float* Wc1  = (const float*)d_in[12];
    const float* bc1  = (const float*)d_in[13];
    const float* Wc2  = (const float*)d_in[14];
    float* out = (float*)d_out;

    int* flag = (int*)d_ws;
    float* biasC = (float*)((char*)d_ws + WS_BIAS_OFF);
    float* W1ea  = (float*)((char*)d_ws + WS_W1EA_OFF);
    unsigned short* W1s = (unsigned short*)((char*)d_ws + WS_W1S_OFF);
    unsigned short* W2s = (unsigned short*)((char*)d_ws + WS_W2S_OFF);

    detect_idx_kernel<<<1, 64, 0, stream>>>((const unsigned int*)ei, flag);

    const int ntot4 = (N_NODES * NODE_DIM + N_NODES * 3) / 4;
    init_out_kernel<<<(ntot4 + 255) / 256, 256, 0, stream>>>(
        (const float4*)h, (const float4*)x, (float4*)out);

    prep1_kernel<<<(32 * 512 + 512 + 255) / 256, 256, 0, stream>>>(
        Wn1, Wc1, bn1, bc1, We2, be2, W1ea, biasC);

    prep2_kernel<<<(512 * 288 + 128 * 256 + 255) / 256, 256, 0, stream>>>(
        Wn1, Wc1, Wn2, W1ea, W1s, W2s);

    egnn_mfma_kernel<<<N_EDGES / TE, 256, 0, stream>>>(
        h, x, ei, dist, We1, be1, bn2, Wc2, biasC, W1s, W2s, flag, out);
}

// Round 5
// 518.343 us; speedup vs baseline: 5.3170x; 1.1789x over previous
//
#include <hip/hip_runtime.h>
#include <math.h>

#define N_NODES 32768
#define N_EDGES 524288
#define NODE_DIM 128
#define HIDDEN 256
#define EDGE_DIM 32
#define TE 32              // edges per block
#define ASTR 296           // smA row stride (bf16): 592 B, 16B-aligned
#define HSTR 264           // smH row stride (bf16): 528 B, 16B-aligned
#define MSTR 132           // smM row stride (f32): 528 B, 16B-aligned

typedef __attribute__((ext_vector_type(8))) short bf16x8;
typedef __attribute__((ext_vector_type(16))) float f32x16;

__device__ __forceinline__ float silu_f(float v) {
    float e = __expf(-v);
    return v * __builtin_amdgcn_rcpf(1.0f + e);
}

__device__ __forceinline__ unsigned short f2bf_rne(float f) {
    union { float f; unsigned int u; } v; v.f = f;
    return (unsigned short)((v.u + 0x7fffu + ((v.u >> 16) & 1u)) >> 16);
}

// half-up pack of two floats -> (bf16(a) | bf16(b)<<16)
__device__ __forceinline__ unsigned int pkbf(float a, float b) {
    union { float f; unsigned int u; } ua, ub; ua.f = a; ub.f = b;
    return __builtin_amdgcn_perm(ub.u + 0x8000u, ua.u + 0x8000u, 0x07060302u);
}
__device__ __forceinline__ unsigned short f2bf_hu(float f) {
    union { float f; unsigned int u; } v; v.f = f;
    return (unsigned short)((v.u + 0x8000u) >> 16);
}

// ws layout (bytes):
//   0       : idx-width flag
//   1024    : biasC f32[512]
//   4096    : W1ea f32[32][512]
//   69632   : W1s bf16 swizzled (512 n x 288 k)
//   364544  : W2s bf16 swizzled (128 d x 256 k)
//   430080  : counts  int[32768]
//   561152  : cursor  int[32768]
//   692224  : perm    int[524288]
#define WS_BIAS_OFF 1024
#define WS_W1EA_OFF 4096
#define WS_W1S_OFF  69632
#define WS_W2S_OFF  364544
#define WS_CNT_OFF  430080
#define WS_CUR_OFF  561152
#define WS_PERM_OFF 692224

__global__ void detect_idx_kernel(const unsigned int* __restrict__ ew, int* __restrict__ flag) {
    if (threadIdx.x == 0 && blockIdx.x == 0) {
        int is64 = 1;
        for (int i = 0; i < 64; ++i)
            if (ew[2 * i + 1] != 0u) { is64 = 0; break; }
        *flag = is64;
    }
}

__global__ void zero_counts_kernel(int* __restrict__ counts) {
    int i = blockIdx.x * 256 + threadIdx.x;
    if (i < N_NODES) counts[i] = 0;
}

__global__ void hist_kernel(const void* __restrict__ ei, const int* __restrict__ flag,
                            int* __restrict__ counts) {
    int e = blockIdx.x * 256 + threadIdx.x;
    int dst = (*flag) ? (int)((const long long*)ei)[N_EDGES + e]
                      : ((const int*)ei)[N_EDGES + e];
    atomicAdd(&counts[dst], 1);
}

// single-block exclusive scan of 32768 counts -> cursor
__global__ __launch_bounds__(1024)
void scan_kernel(const int* __restrict__ counts, int* __restrict__ cursor) {
    __shared__ int part[1024];
    const int t = threadIdx.x;
    const int base = t * 32;
    int loc[32];
    int s = 0;
    #pragma unroll
    for (int i = 0; i < 32; ++i) { loc[i] = s; s += counts[base + i]; }
    part[t] = s;
    __syncthreads();
    #pragma unroll
    for (int d = 1; d < 1024; d <<= 1) {
        int v = (t >= d) ? part[t - d] : 0;
        __syncthreads();
        part[t] += v;
        __syncthreads();
    }
    int excl = part[t] - s;
    #pragma unroll
    for (int i = 0; i < 32; ++i) cursor[base + i] = excl + loc[i];
}

__global__ void place_kernel(const void* __restrict__ ei, const int* __restrict__ flag,
                             int* __restrict__ cursor, int* __restrict__ perm) {
    int e = blockIdx.x * 256 + threadIdx.x;
    int dst = (*flag) ? (int)((const long long*)ei)[N_EDGES + e]
                      : ((const int*)ei)[N_EDGES + e];
    int pos = atomicAdd(&cursor[dst], 1);
    perm[pos] = e;
}

__global__ void init_out_kernel(const float4* __restrict__ h4, const float4* __restrict__ x4,
                                float4* __restrict__ out4) {
    const int NH4 = N_NODES * NODE_DIM / 4;
    const int NX4 = N_NODES * 3 / 4;
    int i = blockIdx.x * blockDim.x + threadIdx.x;
    if (i < NH4) out4[i] = h4[i];
    else if (i < NH4 + NX4) out4[i] = x4[i - NH4];
}

__global__ void prep1_kernel(const float* __restrict__ Wn1, const float* __restrict__ Wc1,
                             const float* __restrict__ bn1, const float* __restrict__ bc1,
                             const float* __restrict__ We2, const float* __restrict__ be2,
                             float* __restrict__ W1ea, float* __restrict__ biasC) {
    int i = blockIdx.x * 256 + threadIdx.x;
    if (i < 32 * 512) {
        int n = i & 511, j = i >> 9;
        float s = 0.0f;
        #pragma unroll 8
        for (int k = 0; k < 32; ++k)
            s += We2[j * 32 + k] * ((n < 256) ? Wn1[(256 + k) * 256 + n]
                                              : Wc1[(256 + k) * 256 + (n - 256)]);
        W1ea[i] = s;
    } else if (i < 32 * 512 + 512) {
        int n = i - 32 * 512;
        float s = (n < 256) ? bn1[n] : bc1[n - 256];
        #pragma unroll 8
        for (int k = 0; k < 32; ++k)
            s += be2[k] * ((n < 256) ? Wn1[(256 + k) * 256 + n]
                                     : Wc1[(256 + k) * 256 + (n - 256)]);
        biasC[n] = s;
    }
}

// B-fragment order for mfma_f32_32x32x16_bf16:
// idx = ((tile*STEPS + step)*64 + lane)*8 + jj ; n = tile*32+(lane&31); k = step*16+(lane>>5)*8+jj
__global__ void prep2_kernel(const float* __restrict__ Wn1, const float* __restrict__ Wc1,
                             const float* __restrict__ Wn2, const float* __restrict__ W1ea,
                             unsigned short* __restrict__ W1s, unsigned short* __restrict__ W2s) {
    int i = blockIdx.x * 256 + threadIdx.x;
    if (i < 512 * 288) {
        int jj = i & 7, lane = (i >> 3) & 63, rest = i >> 9;
        int step = rest % 18, tile = rest / 18;
        int n = tile * 32 + (lane & 31);
        int k = step * 16 + ((lane >> 5) * 8) + jj;
        float v;
        if (k < 256) v = (n < 256) ? Wn1[k * 256 + n] : Wc1[k * 256 + (n - 256)];
        else         v = W1ea[(k - 256) * 512 + n];
        W1s[i] = f2bf_rne(v);
    } else {
        int i2 = i - 512 * 288;
        if (i2 < 128 * 256) {
            int jj = i2 & 7, lane = (i2 >> 3) & 63, rest = i2 >> 9;
            int step = rest & 15, tile = rest >> 4;
            int d = tile * 32 + (lane & 31);
            int k = step * 16 + ((lane >> 5) * 8) + jj;
            W2s[i2] = f2bf_rne(Wn2[k * 128 + d]);
        }
    }
}

__global__ __launch_bounds__(256, 4)
void egnn_mfma_kernel(const float* __restrict__ h, const float* __restrict__ x,
                      const void* __restrict__ ei, const float* __restrict__ dist,
                      const float* __restrict__ We1, const float* __restrict__ be1,
                      const float* __restrict__ bn2, const float* __restrict__ Wc2,
                      const float* __restrict__ biasC,
                      const unsigned short* __restrict__ W1s,
                      const unsigned short* __restrict__ W2s,
                      const int* __restrict__ perm,
                      const int* __restrict__ flag,
                      float* __restrict__ out)
{
    __shared__ unsigned short smA[TE * ASTR];   // GEMM1 A-tile; later reused as smM (f32 m)
    __shared__ unsigned short smH[TE * HSTR];   // GEMM2 A-tile; later reused as coord vecs
    __shared__ int sidx[TE], didx[TE], eidx[TE];
    __shared__ float cw_s[TE];

    const int t = threadIdx.x;
    const int lane = t & 63;
    const int wv = t >> 6;
    const int lo = lane & 31;
    const int hi = lane >> 5;
    const int ebase = blockIdx.x * TE;
    const int is64 = *flag;

    // ---- 1. permuted edge indices + zero cw ----
    if (t < 2 * TE) {
        int e = t & (TE - 1);
        int eid = perm[ebase + e];
        int which = t >> 5;              // 0 = src, 1 = dst
        long long pos = (long long)which * N_EDGES + eid;
        int idx = is64 ? (int)((const long long*)ei)[pos] : ((const int*)ei)[pos];
        if (which == 0) { sidx[e] = idx; eidx[e] = eid; }
        else didx[e] = idx;
        if (t < TE) cw_s[t] = 0.0f;
    }
    __syncthreads();

    // ---- 2a. gather h[src], h[dst] -> bf16 smA ----
    #pragma unroll
    for (int it = 0; it < 4; ++it) {
        int id = it * 256 + t;
        int g8 = id & 15;
        int half = (id >> 4) & 1;
        int e = id >> 5;
        int node = half ? didx[e] : sidx[e];
        const float4* p = (const float4*)&h[node * NODE_DIM + 8 * g8];
        float4 v0 = p[0], v1 = p[1];
        unsigned int a0 = pkbf(v0.x, v0.y), a1 = pkbf(v0.z, v0.w);
        unsigned int a2 = pkbf(v1.x, v1.y), a3 = pkbf(v1.z, v1.w);
        *(uint4*)&smA[e * ASTR + half * NODE_DIM + 8 * g8] = make_uint4(a0, a1, a2, a3);
    }
    // ---- 2b. t1 = silu(d*We1+be1) -> smA[:,256:288] ----
    {
        int e = t >> 3;
        int j4 = (t & 7) * 4;
        float d = dist[eidx[e]];
        float s0 = silu_f(d * We1[j4 + 0] + be1[j4 + 0]);
        float s1 = silu_f(d * We1[j4 + 1] + be1[j4 + 1]);
        float s2 = silu_f(d * We1[j4 + 2] + be1[j4 + 2]);
        float s3 = silu_f(d * We1[j4 + 3] + be1[j4 + 3]);
        *(uint2*)&smA[e * ASTR + 2 * NODE_DIM + j4] = make_uint2(pkbf(s0, s1), pkbf(s2, s3));
    }
    __syncthreads();

    // ---- 3. GEMM1: [32 x 288] @ [288 x 512], 4 n-tiles/wave, prefetch-1 ----
    f32x16 acc0, acc1, acc2, acc3;
    {
        int nb = wv * 128 + lo;
        float b0 = biasC[nb], b1 = biasC[nb + 32], b2 = biasC[nb + 64], b3 = biasC[nb + 96];
        #pragma unroll
        for (int r = 0; r < 16; ++r) { acc0[r] = b0; acc1[r] = b1; acc2[r] = b2; acc3[r] = b3; }
    }
    {
        const int aoff = lo * ASTR + hi * 8;
        const int TS = 18 * 64 * 8;
        int base = ((wv * 4 * 18) * 64 + lane) * 8;
        bf16x8 a_c = *(const bf16x8*)&smA[aoff];
        bf16x8 b0c = *(const bf16x8*)&W1s[base];
        bf16x8 b1c = *(const bf16x8*)&W1s[base + TS];
        bf16x8 b2c = *(const bf16x8*)&W1s[base + 2 * TS];
        bf16x8 b3c = *(const bf16x8*)&W1s[base + 3 * TS];
        #pragma unroll
        for (int step = 0; step < 18; ++step) {
            bf16x8 a_n, b0n, b1n, b2n, b3n;
            if (step < 17) {
                int nb2 = base + (step + 1) * 512;
                a_n = *(const bf16x8*)&smA[aoff + (step + 1) * 16];
                b0n = *(const bf16x8*)&W1s[nb2];
                b1n = *(const bf16x8*)&W1s[nb2 + TS];
                b2n = *(const bf16x8*)&W1s[nb2 + 2 * TS];
                b3n = *(const bf16x8*)&W1s[nb2 + 3 * TS];
            }
            acc0 = __builtin_amdgcn_mfma_f32_32x32x16_bf16(a_c, b0c, acc0, 0, 0, 0);
            acc1 = __builtin_amdgcn_mfma_f32_32x32x16_bf16(a_c, b1c, acc1, 0, 0, 0);
            acc2 = __builtin_amdgcn_mfma_f32_32x32x16_bf16(a_c, b2c, acc2, 0, 0, 0);
            acc3 = __builtin_amdgcn_mfma_f32_32x32x16_bf16(a_c, b3c, acc3, 0, 0, 0);
            if (step < 17) { a_c = a_n; b0c = b0n; b1c = b1n; b2c = b2n; b3c = b3n; }
        }
    }

    // ---- 4. epilogue: silu -> smH (waves 0-1); c-path dot Wc2 (waves 2-3) ----
    const int rowbase = 4 * hi;
    if (wv < 2) {
        int jb = wv * 128 + lo;
        #pragma unroll
        for (int r = 0; r < 16; ++r) {
            int e = (r & 3) + 8 * (r >> 2) + rowbase;
            unsigned short* row = &smH[e * HSTR + jb];
            row[0]  = f2bf_hu(silu_f(acc0[r]));
            row[32] = f2bf_hu(silu_f(acc1[r]));
            row[64] = f2bf_hu(silu_f(acc2[r]));
            row[96] = f2bf_hu(silu_f(acc3[r]));
        }
    } else {
        int nc = (wv - 2) * 128 + lo;
        float w0 = Wc2[nc], w1 = Wc2[nc + 32], w2 = Wc2[nc + 64], w3 = Wc2[nc + 96];
        float p[16];
        #pragma unroll
        for (int r = 0; r < 16; ++r)
            p[r] = silu_f(acc0[r]) * w0 + silu_f(acc1[r]) * w1
                 + silu_f(acc2[r]) * w2 + silu_f(acc3[r]) * w3;
        #pragma unroll
        for (int off = 1; off < 32; off <<= 1) {
            #pragma unroll
            for (int r = 0; r < 16; ++r) p[r] += __shfl_xor(p[r], off);
        }
        if (lo == 0) {
            #pragma unroll
            for (int r = 0; r < 16; ++r) {
                int e = (r & 3) + 8 * (r >> 2) + rowbase;
                atomicAdd(&cw_s[e], p[r]);
            }
        }
    }
    __syncthreads();

    // ---- 5. GEMM2: [32 x 256] @ [256 x 128] -> m tile into LDS (no atomics yet) ----
    float* smM = (float*)smA;            // [e][MSTR] f32 — smA is dead after GEMM1
    float* cx = (float*)smH;             // smH dead after GEMM2 reads below
    float* cy = cx + TE;
    float* cz = cy + TE;
    {
        const int d = wv * 32 + lo;
        f32x16 acc;
        float b = bn2[d];
        #pragma unroll
        for (int r = 0; r < 16; ++r) acc[r] = b;
        const int hoff = lo * HSTR + hi * 8;
        const int wb = ((wv * 16) * 64 + lane) * 8;
        bf16x8 A[2][4], B[2][4];
        #pragma unroll
        for (int j = 0; j < 4; ++j) {
            A[0][j] = *(const bf16x8*)&smH[hoff + j * 16];
            B[0][j] = *(const bf16x8*)&W2s[wb + j * 512];
        }
        #pragma unroll
        for (int sb = 0; sb < 4; ++sb) {
            int cur = sb & 1, nxt = cur ^ 1;
            if (sb < 3) {
                #pragma unroll
                for (int j = 0; j < 4; ++j) {
                    A[nxt][j] = *(const bf16x8*)&smH[hoff + (4 * (sb + 1) + j) * 16];
                    B[nxt][j] = *(const bf16x8*)&W2s[wb + (4 * (sb + 1) + j) * 512];
                }
            }
            #pragma unroll
            for (int j = 0; j < 4; ++j)
                acc = __builtin_amdgcn_mfma_f32_32x32x16_bf16(A[cur][j], B[cur][j], acc, 0, 0, 0);
        }
        __syncthreads();                 // all waves done reading smH / past GEMM1 smA reads
        #pragma unroll
        for (int r = 0; r < 16; ++r) {
            int e = (r & 3) + 8 * (r >> 2) + rowbase;
            smM[e * MSTR + d] = acc[r];
        }
    }
    // per-edge coordinate vectors into LDS
    if (t < TE) {
        int s = sidx[t], dn = didx[t];
        float dx = x[s * 3 + 0] - x[dn * 3 + 0];
        float dy = x[s * 3 + 1] - x[dn * 3 + 1];
        float dz = x[s * 3 + 2] - x[dn * 3 + 2];
        float len = fmaxf(sqrtf(dx * dx + dy * dy + dz * dz), 1e-8f);
        float w = cw_s[t] / len;
        cx[t] = w * dx; cy[t] = w * dy; cz[t] = w * dz;
    }
    __syncthreads();

    // ---- 6. run-reduction over sorted dst + sparse atomics ----
    {
        const int g = t >> 5;            // 8 edge-strided groups
        const int d4 = (t & 31) * 4;
        for (int e0 = g; e0 < TE; e0 += 8) {
            if (e0 > 0 && didx[e0] == didx[e0 - 1]) continue;   // not a run leader
            float4 s = *(const float4*)&smM[e0 * MSTR + d4];
            int er = e0 + 1;
            while (er < TE && didx[er] == didx[e0]) {
                float4 v = *(const float4*)&smM[er * MSTR + d4];
                s.x += v.x; s.y += v.y; s.z += v.z; s.w += v.w;
                ++er;
            }
            float* dp = &out[didx[e0] * NODE_DIM + d4];
            atomicAdd(dp + 0, s.x); atomicAdd(dp + 1, s.y);
            atomicAdd(dp + 2, s.z); atomicAdd(dp + 3, s.w);
        }
    }
    if (t < TE) {
        int e0 = t;
        if (e0 == 0 || didx[e0] != didx[e0 - 1]) {
            float sx = cx[e0], sy = cy[e0], sz = cz[e0];
            int er = e0 + 1;
            while (er < TE && didx[er] == didx[e0]) {
                sx += cx[er]; sy += cy[er]; sz += cz[er];
                ++er;
            }
            float* xo = out + N_NODES * NODE_DIM + didx[e0] * 3;
            atomicAdd(xo + 0, sx); atomicAdd(xo + 1, sy); atomicAdd(xo + 2, sz);
        }
    }
}

extern "C" void kernel_launch(void* const* d_in, const int* in_sizes, int n_in,
                              void* d_out, int out_size, void* d_ws, size_t ws_size,
                              hipStream_t stream) {
    const float* h    = (const float*)d_in[0];
    const float* x    = (const float*)d_in[1];
    const void*  ei   = d_in[2];
    const float* dist = (const float*)d_in[3];
    const float* We1  = (const float*)d_in[4];
    const float* be1  = (const float*)d_in[5];
    const float* We2  = (const float*)d_in[6];
    const float* be2  = (const float*)d_in[7];
    const float* Wn1  = (const float*)d_in[8];
    const float* bn1  = (const float*)d_in[9];
    const float* Wn2  = (const float*)d_in[10];
    const float* bn2  = (const float*)d_in[11];
    const float* Wc1  = (const float*)d_in[12];
    const float* bc1  = (const float*)d_in[13];
    const float* Wc2  = (const float*)d_in[14];
    float* out = (float*)d_out;

    int* flag = (int*)d_ws;
    float* biasC = (float*)((char*)d_ws + WS_BIAS_OFF);
    float* W1ea  = (float*)((char*)d_ws + WS_W1EA_OFF);
    unsigned short* W1s = (unsigned short*)((char*)d_ws + WS_W1S_OFF);
    unsigned short* W2s = (unsigned short*)((char*)d_ws + WS_W2S_OFF);
    int* counts = (int*)((char*)d_ws + WS_CNT_OFF);
    int* cursor = (int*)((char*)d_ws + WS_CUR_OFF);
    int* perm   = (int*)((char*)d_ws + WS_PERM_OFF);

    detect_idx_kernel<<<1, 64, 0, stream>>>((const unsigned int*)ei, flag);

    // counting sort of edges by dst
    zero_counts_kernel<<<N_NODES / 256, 256, 0, stream>>>(counts);
    hist_kernel<<<N_EDGES / 256, 256, 0, stream>>>(ei, flag, counts);
    scan_kernel<<<1, 1024, 0, stream>>>(counts, cursor);
    place_kernel<<<N_EDGES / 256, 256, 0, stream>>>(ei, flag, cursor, perm);

    const int ntot4 = (N_NODES * NODE_DIM + N_NODES * 3) / 4;
    init_out_kernel<<<(ntot4 + 255) / 256, 256, 0, stream>>>(
        (const float4*)h, (const float4*)x, (float4*)out);

    prep1_kernel<<<(32 * 512 + 512 + 255) / 256, 256, 0, stream>>>(
        Wn1, Wc1, bn1, bc1, We2, be2, W1ea, biasC);

    prep2_kernel<<<(512 * 288 + 128 * 256 + 255) / 256, 256, 0, stream>>>(
        Wn1, Wc1, Wn2, W1ea, W1s, W2s);

    egnn_mfma_kernel<<<N_EDGES / TE, 256, 0, stream>>>(
        h, x, ei, dist, We1, be1, bn2, Wc2, biasC, W1s, W2s, perm, flag, out);
}

// Round 6
// 487.354 us; speedup vs baseline: 5.6551x; 1.0636x over previous
//
#include <hip/hip_runtime.h>
#include <math.h>

#define N_NODES 32768
#define N_EDGES 524288
#define NODE_DIM 128
#define HIDDEN 256
#define EDGE_DIM 32
#define TE 64              // edges per block
#define ASTR 296           // smA row stride (bf16): 592 B, 16B-aligned
#define HSTR 264           // smH row stride (bf16): 528 B, 16B-aligned
#define MSTR 132           // smM row stride (f32): 528 B, 16B-aligned

typedef __attribute__((ext_vector_type(8))) short bf16x8;
typedef __attribute__((ext_vector_type(16))) float f32x16;

__device__ __forceinline__ float silu_f(float v) {
    float e = __expf(-v);
    return v * __builtin_amdgcn_rcpf(1.0f + e);
}

__device__ __forceinline__ unsigned short f2bf_rne(float f) {
    union { float f; unsigned int u; } v; v.f = f;
    return (unsigned short)((v.u + 0x7fffu + ((v.u >> 16) & 1u)) >> 16);
}

// half-up pack of two floats -> (bf16(a) | bf16(b)<<16)
__device__ __forceinline__ unsigned int pkbf(float a, float b) {
    union { float f; unsigned int u; } ua, ub; ua.f = a; ub.f = b;
    return __builtin_amdgcn_perm(ub.u + 0x8000u, ua.u + 0x8000u, 0x07060302u);
}
__device__ __forceinline__ unsigned short f2bf_hu(float f) {
    union { float f; unsigned int u; } v; v.f = f;
    return (unsigned short)((v.u + 0x8000u) >> 16);
}

// ws layout (bytes):
//   0       : idx-width flag
//   1024    : biasC f32[512]
//   69632   : W1s bf16 swizzled (16 n-tiles x 18 steps x 64 lanes x 8)
//   364544  : W2s bf16 swizzled (4 d-tiles x 16 steps x 64 lanes x 8)
//   430080  : counts  int[32768]
//   561152  : cursor  int[32768]
//   692224  : perm    int[524288]
#define WS_BIAS_OFF 1024
#define WS_W1S_OFF  69632
#define WS_W2S_OFF  364544
#define WS_CNT_OFF  430080
#define WS_CUR_OFF  561152
#define WS_PERM_OFF 692224

// detect idx width + zero the histogram in one launch
__global__ void detect_zero_kernel(const unsigned int* __restrict__ ew, int* __restrict__ flag,
                                   int* __restrict__ counts) {
    int i = blockIdx.x * 256 + threadIdx.x;
    if (i < N_NODES) counts[i] = 0;
    if (i == 0) {
        int is64 = 1;
        for (int k = 0; k < 64; ++k)
            if (ew[2 * k + 1] != 0u) { is64 = 0; break; }
        *flag = is64;
    }
}

__global__ void hist_kernel(const void* __restrict__ ei, const int* __restrict__ flag,
                            int* __restrict__ counts) {
    int e = blockIdx.x * 256 + threadIdx.x;
    int dst = (*flag) ? (int)((const long long*)ei)[N_EDGES + e]
                      : ((const int*)ei)[N_EDGES + e];
    atomicAdd(&counts[dst], 1);
}

// single-block exclusive scan of 32768 counts -> cursor
__global__ __launch_bounds__(1024)
void scan_kernel(const int* __restrict__ counts, int* __restrict__ cursor) {
    __shared__ int part[1024];
    const int t = threadIdx.x;
    const int base = t * 32;
    int loc[32];
    int s = 0;
    #pragma unroll
    for (int i = 0; i < 32; ++i) { loc[i] = s; s += counts[base + i]; }
    part[t] = s;
    __syncthreads();
    #pragma unroll
    for (int d = 1; d < 1024; d <<= 1) {
        int v = (t >= d) ? part[t - d] : 0;
        __syncthreads();
        part[t] += v;
        __syncthreads();
    }
    int excl = part[t] - s;
    #pragma unroll
    for (int i = 0; i < 32; ++i) cursor[base + i] = excl + loc[i];
}

__global__ void place_kernel(const void* __restrict__ ei, const int* __restrict__ flag,
                             int* __restrict__ cursor, int* __restrict__ perm) {
    int e = blockIdx.x * 256 + threadIdx.x;
    int dst = (*flag) ? (int)((const long long*)ei)[N_EDGES + e]
                      : ((const int*)ei)[N_EDGES + e];
    int pos = atomicAdd(&cursor[dst], 1);
    perm[pos] = e;
}

__global__ void init_out_kernel(const float4* __restrict__ h4, const float4* __restrict__ x4,
                                float4* __restrict__ out4) {
    const int NH4 = N_NODES * NODE_DIM / 4;
    const int NX4 = N_NODES * 3 / 4;
    int i = blockIdx.x * blockDim.x + threadIdx.x;
    if (i < NH4) out4[i] = h4[i];
    else if (i < NH4 + NX4) out4[i] = x4[i - NH4];
}

// prep: swizzle weights into B-fragment order; edge-MLP layer-2 folded on the fly.
// frag idx = ((tile*STEPS + step)*64 + lane)*8 + jj ; n = tile*32+(lane&31); k = step*16+(lane>>5)*8+jj
__global__ void prep_kernel(const float* __restrict__ Wn1, const float* __restrict__ Wc1,
                            const float* __restrict__ Wn2,
                            const float* __restrict__ bn1, const float* __restrict__ bc1,
                            const float* __restrict__ We2, const float* __restrict__ be2,
                            unsigned short* __restrict__ W1s, unsigned short* __restrict__ W2s,
                            float* __restrict__ biasC) {
    int i = blockIdx.x * 256 + threadIdx.x;
    if (i < 512 * 288) {
        int jj = i & 7, lane = (i >> 3) & 63, rest = i >> 9;
        int step = rest % 18, tile = rest / 18;
        int n = tile * 32 + (lane & 31);
        int k = step * 16 + ((lane >> 5) * 8) + jj;
        float v;
        if (k < 256) {
            v = (n < 256) ? Wn1[k * 256 + n] : Wc1[k * 256 + (n - 256)];
        } else {
            int j = k - 256;           // folded: v = We2[j,:] . W1[256:288, n]
            float s = 0.0f;
            #pragma unroll 8
            for (int q = 0; q < 32; ++q)
                s += We2[j * 32 + q] * ((n < 256) ? Wn1[(256 + q) * 256 + n]
                                                  : Wc1[(256 + q) * 256 + (n - 256)]);
            v = s;
        }
        W1s[i] = f2bf_rne(v);
    } else if (i < 512 * 288 + 128 * 256) {
        int i2 = i - 512 * 288;
        int jj = i2 & 7, lane = (i2 >> 3) & 63, rest = i2 >> 9;
        int step = rest & 15, tile = rest >> 4;
        int d = tile * 32 + (lane & 31);
        int k = step * 16 + ((lane >> 5) * 8) + jj;
        W2s[i2] = f2bf_rne(Wn2[k * 128 + d]);
    } else if (i < 512 * 288 + 128 * 256 + 512) {
        int n = i - (512 * 288 + 128 * 256);
        float s = (n < 256) ? bn1[n] : bc1[n - 256];
        #pragma unroll 8
        for (int q = 0; q < 32; ++q)
            s += be2[q] * ((n < 256) ? Wn1[(256 + q) * 256 + n]
                                     : Wc1[(256 + q) * 256 + (n - 256)]);
        biasC[n] = s;
    }
}

__global__ __launch_bounds__(512, 4)
void egnn_mfma_kernel(const float* __restrict__ h, const float* __restrict__ x,
                      const void* __restrict__ ei, const float* __restrict__ dist,
                      const float* __restrict__ We1, const float* __restrict__ be1,
                      const float* __restrict__ bn2, const float* __restrict__ Wc2,
                      const float* __restrict__ biasC,
                      const unsigned short* __restrict__ W1s,
                      const unsigned short* __restrict__ W2s,
                      const int* __restrict__ perm,
                      const int* __restrict__ flag,
                      float* __restrict__ out)
{
    // one overlapped region: smA (GEMM1 A) -> smH (GEMM2 A) -> smM (f32 m tile)
    __shared__ unsigned short smA[TE * ASTR];          // 37888 B
    __shared__ int sidx[TE], didx[TE], eidx[TE];
    __shared__ float cw_s[TE];
    __shared__ float cxyz[3 * TE];

    unsigned short* smH = smA;                          // TE*HSTR*2 = 33792 B
    float* smM = (float*)smA;                           // TE*MSTR*4 = 33792 B

    const int t = threadIdx.x;
    const int lane = t & 63;
    const int wv = t >> 6;       // 0..7
    const int lo = lane & 31;
    const int hi = lane >> 5;
    const int ebase = blockIdx.x * TE;
    const int is64 = *flag;

    // ---- 1. permuted edge indices + zero cw ----
    if (t < 2 * TE) {
        int e = t & (TE - 1);
        int eid = perm[ebase + e];
        int which = t >> 6;              // 0 = src, 1 = dst
        long long pos = (long long)which * N_EDGES + eid;
        int idx = is64 ? (int)((const long long*)ei)[pos] : ((const int*)ei)[pos];
        if (which == 0) { sidx[e] = idx; eidx[e] = eid; }
        else didx[e] = idx;
        if (t < TE) cw_s[t] = 0.0f;
    }
    __syncthreads();

    // ---- 2a. gather h[src], h[dst] -> bf16 smA ----
    #pragma unroll
    for (int it = 0; it < 4; ++it) {
        int id = it * 512 + t;
        int g8 = id & 15;
        int half = (id >> 4) & 1;
        int e = id >> 5;
        int node = half ? didx[e] : sidx[e];
        const float4* p = (const float4*)&h[node * NODE_DIM + 8 * g8];
        float4 v0 = p[0], v1 = p[1];
        unsigned int a0 = pkbf(v0.x, v0.y), a1 = pkbf(v0.z, v0.w);
        unsigned int a2 = pkbf(v1.x, v1.y), a3 = pkbf(v1.z, v1.w);
        *(uint4*)&smA[e * ASTR + half * NODE_DIM + 8 * g8] = make_uint4(a0, a1, a2, a3);
    }
    // ---- 2b. t1 = silu(d*We1+be1) -> smA[:,256:288] ----
    {
        int e = t >> 3;
        int j4 = (t & 7) * 4;
        float d = dist[eidx[e]];
        float s0 = silu_f(d * We1[j4 + 0] + be1[j4 + 0]);
        float s1 = silu_f(d * We1[j4 + 1] + be1[j4 + 1]);
        float s2 = silu_f(d * We1[j4 + 2] + be1[j4 + 2]);
        float s3 = silu_f(d * We1[j4 + 3] + be1[j4 + 3]);
        *(uint2*)&smA[e * ASTR + 2 * NODE_DIM + j4] = make_uint2(pkbf(s0, s1), pkbf(s2, s3));
    }
    __syncthreads();

    // ---- 3. GEMM1: [64 x 288] @ [288 x 512]; wave: 2 e-tiles x 2 n-tiles ----
    f32x16 a00, a01, a10, a11;           // [et][nt]
    {
        int nb = wv * 64 + lo;
        float b0 = biasC[nb], b1 = biasC[nb + 32];
        #pragma unroll
        for (int r = 0; r < 16; ++r) { a00[r] = b0; a01[r] = b1; a10[r] = b0; a11[r] = b1; }
    }
    {
        const int aoff0 = lo * ASTR + hi * 8;
        const int aoff1 = (32 + lo) * ASTR + hi * 8;
        const int TS = 18 * 64 * 8;
        const int base = ((wv * 2 * 18) * 64 + lane) * 8;
        bf16x8 b0c = *(const bf16x8*)&W1s[base];
        bf16x8 b1c = *(const bf16x8*)&W1s[base + TS];
        #pragma unroll
        for (int step = 0; step < 18; ++step) {
            bf16x8 b0n, b1n;
            if (step < 17) {
                b0n = *(const bf16x8*)&W1s[base + (step + 1) * 512];
                b1n = *(const bf16x8*)&W1s[base + (step + 1) * 512 + TS];
            }
            bf16x8 f0 = *(const bf16x8*)&smA[aoff0 + step * 16];
            bf16x8 f1 = *(const bf16x8*)&smA[aoff1 + step * 16];
            a00 = __builtin_amdgcn_mfma_f32_32x32x16_bf16(f0, b0c, a00, 0, 0, 0);
            a10 = __builtin_amdgcn_mfma_f32_32x32x16_bf16(f1, b0c, a10, 0, 0, 0);
            a01 = __builtin_amdgcn_mfma_f32_32x32x16_bf16(f0, b1c, a01, 0, 0, 0);
            a11 = __builtin_amdgcn_mfma_f32_32x32x16_bf16(f1, b1c, a11, 0, 0, 0);
            if (step < 17) { b0c = b0n; b1c = b1n; }
        }
    }
    __syncthreads();                     // all smA reads done before smH overwrite

    // ---- 4. epilogue: waves 0-3 n-path -> silu -> smH; waves 4-7 c-path ----
    const int rowbase = 4 * hi;
    if (wv < 4) {
        int jb = wv * 64 + lo;
        #pragma unroll
        for (int r = 0; r < 16; ++r) {
            int er = (r & 3) + 8 * (r >> 2) + rowbase;
            unsigned short* row0 = &smH[er * HSTR + jb];
            unsigned short* row1 = &smH[(er + 32) * HSTR + jb];
            row0[0]  = f2bf_hu(silu_f(a00[r]));
            row0[32] = f2bf_hu(silu_f(a01[r]));
            row1[0]  = f2bf_hu(silu_f(a10[r]));
            row1[32] = f2bf_hu(silu_f(a11[r]));
        }
    } else {
        int nc = (wv - 4) * 64 + lo;
        float w0 = Wc2[nc], w1 = Wc2[nc + 32];
        float p0[16], p1[16];
        #pragma unroll
        for (int r = 0; r < 16; ++r) {
            p0[r] = silu_f(a00[r]) * w0 + silu_f(a01[r]) * w1;
            p1[r] = silu_f(a10[r]) * w0 + silu_f(a11[r]) * w1;
        }
        #pragma unroll
        for (int off = 1; off < 32; off <<= 1) {
            #pragma unroll
            for (int r = 0; r < 16; ++r) {
                p0[r] += __shfl_xor(p0[r], off);
                p1[r] += __shfl_xor(p1[r], off);
            }
        }
        if (lo == 0) {
            #pragma unroll
            for (int r = 0; r < 16; ++r) {
                int er = (r & 3) + 8 * (r >> 2) + rowbase;
                atomicAdd(&cw_s[er], p0[r]);
                atomicAdd(&cw_s[er + 32], p1[r]);
            }
        }
    }
    __syncthreads();

    // coordinate vectors (needs cw_s complete)
    if (t < TE) {
        int s = sidx[t], dn = didx[t];
        float dx = x[s * 3 + 0] - x[dn * 3 + 0];
        float dy = x[s * 3 + 1] - x[dn * 3 + 1];
        float dz = x[s * 3 + 2] - x[dn * 3 + 2];
        float len = fmaxf(sqrtf(dx * dx + dy * dy + dz * dz), 1e-8f);
        float w = cw_s[t] / len;
        cxyz[t] = w * dx; cxyz[TE + t] = w * dy; cxyz[2 * TE + t] = w * dz;
    }

    // ---- 5. GEMM2: [64 x 256] @ [256 x 128]; wave: (e-tile, d-tile) ----
    {
        const int et = wv >> 2;
        const int dt = wv & 3;
        const int d = dt * 32 + lo;
        f32x16 acc;
        float b = bn2[d];
        #pragma unroll
        for (int r = 0; r < 16; ++r) acc[r] = b;
        const int hoff = (et * 32 + lo) * HSTR + hi * 8;
        const int wb = ((dt * 16) * 64 + lane) * 8;
        bf16x8 bc = *(const bf16x8*)&W2s[wb];
        #pragma unroll
        for (int step = 0; step < 16; ++step) {
            bf16x8 bn_;
            if (step < 15) bn_ = *(const bf16x8*)&W2s[wb + (step + 1) * 512];
            bf16x8 af = *(const bf16x8*)&smH[hoff + step * 16];
            acc = __builtin_amdgcn_mfma_f32_32x32x16_bf16(af, bc, acc, 0, 0, 0);
            if (step < 15) bc = bn_;
        }
        __syncthreads();                 // all smH reads done before smM overwrite
        #pragma unroll
        for (int r = 0; r < 16; ++r) {
            int er = et * 32 + (r & 3) + 8 * (r >> 2) + rowbase;
            smM[er * MSTR + d] = acc[r];
        }
    }
    __syncthreads();

    // ---- 6. run-reduction over sorted dst + sparse atomics ----
    {
        const int g = t >> 5;            // 16 edge-strided groups
        const int d4 = (t & 31) * 4;
        for (int e0 = g; e0 < TE; e0 += 16) {
            if (e0 > 0 && didx[e0] == didx[e0 - 1]) continue;   // not a run leader
            float4 s = *(const float4*)&smM[e0 * MSTR + d4];
            int er = e0 + 1;
            while (er < TE && didx[er] == didx[e0]) {
                float4 v = *(const float4*)&smM[er * MSTR + d4];
                s.x += v.x; s.y += v.y; s.z += v.z; s.w += v.w;
                ++er;
            }
            float* dp = &out[didx[e0] * NODE_DIM + d4];
            atomicAdd(dp + 0, s.x); atomicAdd(dp + 1, s.y);
            atomicAdd(dp + 2, s.z); atomicAdd(dp + 3, s.w);
        }
    }
    if (t < TE) {
        int e0 = t;
        if (e0 == 0 || didx[e0] != didx[e0 - 1]) {
            float sx = cxyz[e0], sy = cxyz[TE + e0], sz = cxyz[2 * TE + e0];
            int er = e0 + 1;
            while (er < TE && didx[er] == didx[e0]) {
                sx += cxyz[er]; sy += cxyz[TE + er]; sz += cxyz[2 * TE + er];
                ++er;
            }
            float* xo = out + N_NODES * NODE_DIM + didx[e0] * 3;
            atomicAdd(xo + 0, sx); atomicAdd(xo + 1, sy); atomicAdd(xo + 2, sz);
        }
    }
}

extern "C" void kernel_launch(void* const* d_in, const int* in_sizes, int n_in,
                              void* d_out, int out_size, void* d_ws, size_t ws_size,
                              hipStream_t stream) {
    const float* h    = (const float*)d_in[0];
    const float* x    = (const float*)d_in[1];
    const void*  ei   = d_in[2];
    const float* dist = (const float*)d_in[3];
    const float* We1  = (const float*)d_in[4];
    const float* be1  = (const float*)d_in[5];
    const float* We2  = (const float*)d_in[6];
    const float* be2  = (const float*)d_in[7];
    const float* Wn1  = (const float*)d_in[8];
    const float* bn1  = (const float*)d_in[9];
    const float* Wn2  = (const float*)d_in[10];
    const float* bn2  = (const float*)d_in[11];
    const float* Wc1  = (const float*)d_in[12];
    const float* bc1  = (const float*)d_in[13];
    const float* Wc2  = (const float*)d_in[14];
    float* out = (float*)d_out;

    int* flag = (int*)d_ws;
    float* biasC = (float*)((char*)d_ws + WS_BIAS_OFF);
    unsigned short* W1s = (unsigned short*)((char*)d_ws + WS_W1S_OFF);
    unsigned short* W2s = (unsigned short*)((char*)d_ws + WS_W2S_OFF);
    int* counts = (int*)((char*)d_ws + WS_CNT_OFF);
    int* cursor = (int*)((char*)d_ws + WS_CUR_OFF);
    int* perm   = (int*)((char*)d_ws + WS_PERM_OFF);

    detect_zero_kernel<<<N_NODES / 256, 256, 0, stream>>>((const unsigned int*)ei, flag, counts);
    hist_kernel<<<N_EDGES / 256, 256, 0, stream>>>(ei, flag, counts);
    scan_kernel<<<1, 1024, 0, stream>>>(counts, cursor);
    place_kernel<<<N_EDGES / 256, 256, 0, stream>>>(ei, flag, cursor, perm);

    const int ntot4 = (N_NODES * NODE_DIM + N_NODES * 3) / 4;
    init_out_kernel<<<(ntot4 + 255) / 256, 256, 0, stream>>>(
        (const float4*)h, (const float4*)x, (float4*)out);

    prep_kernel<<<(512 * 288 + 128 * 256 + 512 + 255) / 256, 256, 0, stream>>>(
        Wn1, Wc1, Wn2, bn1, bc1, We2, be2, W1s, W2s, biasC);

    egnn_mfma_kernel<<<N_EDGES / TE, 512, 0, stream>>>(
        h, x, ei, dist, We1, be1, bn2, Wc2, biasC, W1s, W2s, perm, flag, out);
}